// Round 19
// baseline (154.215 us; speedup 1.0000x reference)
//
#include <hip/hip_runtime.h>
#include <hip/hip_bf16.h>

#define Nn 8192
#define Dd 512
#define KK 16
#define CC 24      // merged candidates per row (rescore input)
#define CSUB 5     // per-lane reservoir size in knn_cand
#define JSPLIT 32  // 32 J-chunks of 256 rows; 4 per XCD
#define PENT 256   // partial entries per row (32 jc x 8)
#define GAPTHR 0.01f  // fp32-vs-fp64 selection gap threshold (err <= 2.5e-4)

typedef int i32x4 __attribute__((ext_vector_type(4)));
typedef unsigned int uint32;

__device__ __forceinline__ uint32 med3u(uint32 a, uint32 b, uint32 c) {
  uint32 d;
  asm("v_med3_u32 %0, %1, %2, %3" : "=v"(d) : "v"(a), "v"(b), "v"(c));
  return d;
}

// Branchless top-k (smallest keys) in a descending-sorted register array.
template <int CCn>
__device__ __forceinline__ void topk_insert(uint32* h, uint32 v) {
#pragma unroll
  for (int s = 0; s < CCn - 1; ++s) h[s] = med3u(h[s], h[s + 1], v);
  h[CCn - 1] = (h[CCn - 1] < v) ? h[CCn - 1] : v;
}

// ---- Barrier-free bitonic: compare-exchange with shfl partner (j <= 32) ----
__device__ __forceinline__ uint32 cswap(uint32 v, int j, bool asc, int lane) {
  uint32 pv = (uint32)__shfl_xor((int)v, j, 64);
  uint32 mn = v < pv ? v : pv;
  uint32 mx = v < pv ? pv : v;
  const bool lower = ((lane & j) == 0);
  return (asc == lower) ? mn : mx;
}

__device__ __forceinline__ void cmpx(uint32& a, uint32& b, bool asc) {
  uint32 mn = a < b ? a : b;
  uint32 mx = a < b ? b : a;
  a = asc ? mn : mx;
  b = asc ? mx : mn;
}

// Full ascending bitonic sort of 256 uint keys, 4 per lane.
__device__ __forceinline__ void sort256(uint32& v0, uint32& v1, uint32& v2,
                                        uint32& v3, int lane) {
#pragma unroll
  for (int k = 2; k <= 32; k <<= 1) {
#pragma unroll
    for (int j = k >> 1; j > 0; j >>= 1) {
      const bool asc = ((lane & k) == 0);
      v0 = cswap(v0, j, asc, lane);
      v1 = cswap(v1, j, asc, lane);
      v2 = cswap(v2, j, asc, lane);
      v3 = cswap(v3, j, asc, lane);
    }
  }
#pragma unroll
  for (int j = 32; j > 0; j >>= 1) {
    v0 = cswap(v0, j, true, lane);
    v1 = cswap(v1, j, false, lane);
    v2 = cswap(v2, j, true, lane);
    v3 = cswap(v3, j, false, lane);
  }
  cmpx(v0, v1, true);
  cmpx(v2, v3, false);
#pragma unroll
  for (int j = 32; j > 0; j >>= 1) {
    v0 = cswap(v0, j, true, lane);
    v1 = cswap(v1, j, true, lane);
    v2 = cswap(v2, j, false, lane);
    v3 = cswap(v3, j, false, lane);
  }
  cmpx(v0, v2, true);
  cmpx(v1, v3, true);
  cmpx(v0, v1, true);
  cmpx(v2, v3, true);
#pragma unroll
  for (int j = 32; j > 0; j >>= 1) {
    v0 = cswap(v0, j, true, lane);
    v1 = cswap(v1, j, true, lane);
    v2 = cswap(v2, j, true, lane);
    v3 = cswap(v3, j, true, lane);
  }
}

// -------- Kernel A: fp32 -> int8 (per-row symmetric), cc'-major frag order --------
// One wave = 2 rows; lane handles 16 cols = exactly one xq frag. No LDS.
__global__ void knn_prep(const float* __restrict__ x, uint4* __restrict__ xq,
                         float2* __restrict__ sqs) {
  const int t = threadIdx.x;
  const int w = t >> 6, l = t & 63;
  const int row = blockIdx.x * 8 + w * 2 + (l >> 5);
  const int cc = l & 31;
  const float4* xr = (const float4*)(x + (size_t)row * Dd + cc * 16);
  float4 a = xr[0], b = xr[1], c = xr[2], d = xr[3];
  float s = 0.f, amax = 0.f;
#pragma unroll
  for (int q = 0; q < 4; ++q) {
    float4 v = (q == 0) ? a : (q == 1) ? b : (q == 2) ? c : d;
    s = fmaf(v.x, v.x, s); s = fmaf(v.y, v.y, s);
    s = fmaf(v.z, v.z, s); s = fmaf(v.w, v.w, s);
    amax = fmaxf(amax, fmaxf(fmaxf(fabsf(v.x), fabsf(v.y)),
                             fmaxf(fabsf(v.z), fabsf(v.w))));
  }
#pragma unroll
  for (int j = 1; j <= 16; j <<= 1) {  // reduce within 32-lane row group
    s += __shfl_xor(s, j);
    amax = fmaxf(amax, __shfl_xor(amax, j));
  }
  const float inv = (amax > 0.f) ? (127.f / amax) : 0.f;
  if (cc == 0) sqs[row] = make_float2(s, amax * (1.f / 127.f));
  uint32 wds[4];
#pragma unroll
  for (int q = 0; q < 4; ++q) {
    float4 v = (q == 0) ? a : (q == 1) ? b : (q == 2) ? c : d;
    const float vv[4] = {v.x, v.y, v.z, v.w};
    uint32 bb = 0;
#pragma unroll
    for (int e = 0; e < 4; ++e) {
      int qi = __float2int_rn(vv[e] * inv);
      bb |= ((uint32)(qi & 0xFF)) << (8 * e);
    }
    wds[q] = bb;
  }
  const int rb = row >> 4, r16 = row & 15;
  xq[((size_t)cc * 512 + rb) * 16 + r16] =
      make_uint4(wds[0], wds[1], wds[2], wds[3]);
}

// ------- Kernel B: barrier-free i8 MFMA (K=64/instr), 64x128 wave tile -------
__global__ __launch_bounds__(256, 2) void knn_cand(
    const uint4* __restrict__ xqv, const float2* __restrict__ sqs,
    uint32* __restrict__ partials) {
  __shared__ uint32 entS[128][41];  // 21 KB
  __shared__ uint32 hS[128][16];    // 8 KB

  const int bid = blockIdx.x;
  const int xcd = bid & 7;
  const int jc = xcd * 4 + ((bid >> 3) & 3);  // [0,32)
  const int ib = bid >> 5;                    // [0,64)
  const int t = threadIdx.x;
  const int w = t >> 6;
  const int l = t & 63;
  const int wrow = w >> 1, wcol = w & 1;
  const int l16 = l & 15, lq = l >> 4;

  const i32x4* xf = (const i32x4*)xqv;
  const int abase = ib * 8 + wrow * 4;
  const int bbase = jc * 16 + wcol * 8;  // 8 rb-blocks = 128 j-rows
  const int jbase = jc * 256;

  const i32x4* pA0 = xf + ((size_t)lq * 512 + abase) * 16 + l16;
  const i32x4* pB0 = xf + ((size_t)lq * 512 + bbase) * 16 + l16;

#define LDSET(fa, fb, s)                                              \
  do {                                                                \
    const i32x4* pa = pA0 + (size_t)(s)*32768;                        \
    const i32x4* pb = pB0 + (size_t)(s)*32768;                        \
    _Pragma("unroll") for (int q = 0; q < 4; ++q) fa[q] = pa[q * 16]; \
    _Pragma("unroll") for (int q = 0; q < 8; ++q) fb[q] = pb[q * 16]; \
  } while (0)

  uint32 heap[4][CSUB];
#pragma unroll
  for (int fi = 0; fi < 4; ++fi)
#pragma unroll
    for (int s = 0; s < CSUB; ++s) heap[fi][s] = 0xFFFFFFFFu;

  i32x4 acc[4][8];
#pragma unroll
  for (int a = 0; a < 4; ++a)
#pragma unroll
    for (int b = 0; b < 8; ++b) acc[a][b] = (i32x4){0, 0, 0, 0};

  i32x4 fa0[4], fb0[8], fa1[4], fb1[8];
  LDSET(fa0, fb0, 0);

#pragma unroll 1
  for (int s = 0; s < 8; s += 2) {
    LDSET(fa1, fb1, s + 1);
    __builtin_amdgcn_s_setprio(1);
#pragma unroll
    for (int fi = 0; fi < 4; ++fi)
#pragma unroll
      for (int fj = 0; fj < 8; ++fj)
        acc[fi][fj] = __builtin_amdgcn_mfma_i32_16x16x64_i8(
            fb0[fj], fa0[fi], acc[fi][fj], 0, 0, 0);  // swapped: C^T
    __builtin_amdgcn_s_setprio(0);
    if (s + 2 < 8) LDSET(fa0, fb0, s + 2);
    __builtin_amdgcn_s_setprio(1);
#pragma unroll
    for (int fi = 0; fi < 4; ++fi)
#pragma unroll
      for (int fj = 0; fj < 8; ++fj)
        acc[fi][fj] = __builtin_amdgcn_mfma_i32_16x16x64_i8(
            fb1[fj], fa1[fi], acc[fi][fj], 0, 0, 0);
    __builtin_amdgcn_s_setprio(0);
  }
#undef LDSET

  // In-register selection: key = sq_j - 2 s_i s_j dot (>=0 clamp).
  float mi[4];
#pragma unroll
  for (int fi = 0; fi < 4; ++fi)
    mi[fi] = -2.f * sqs[ib * 128 + wrow * 64 + fi * 16 + l16].y;
  const uint32 jg_base = (uint32)(jbase + wcol * 128 + lq * 4);
#pragma unroll
  for (int fj = 0; fj < 8; ++fj) {
    const float2* sp = &sqs[jbase + wcol * 128 + fj * 16 + lq * 4];
    float4 p0 = *(const float4*)sp;        // (sq0,s0,sq1,s1)
    float4 p1 = *(const float4*)(sp + 2);  // (sq2,s2,sq3,s3)
    const float sv[4] = {p0.x, p0.z, p1.x, p1.z};
    const float ss[4] = {p0.y, p0.w, p1.y, p1.w};
#pragma unroll
    for (int r = 0; r < 4; ++r) {
      const uint32 jg = jg_base + (uint32)(fj * 16 + r);
#pragma unroll
      for (int fi = 0; fi < 4; ++fi) {
        float key =
            fmaxf(fmaf(mi[fi] * ss[r], (float)acc[fi][fj][r], sv[r]), 0.f);
        uint32 packed = (__builtin_bit_cast(uint32, key) & 0xFFFFE000u) | jg;
        topk_insert<CSUB>(heap[fi], packed);  // self removed in rescore
      }
    }
  }

  // Merge: 8 lane-reservoirs (40 entries) per row -> top-8 per (row, jc).
#pragma unroll
  for (int fi = 0; fi < 4; ++fi)
#pragma unroll
    for (int s = 0; s < CSUB; ++s)
      entS[wrow * 64 + fi * 16 + l16][(wcol * 4 + lq) * CSUB + s] =
          heap[fi][s];
  __syncthreads();

  const int row_s = t >> 1, half = t & 1;
  uint32 mh[8];
#pragma unroll
  for (int s = 0; s < 8; ++s) mh[s] = 0xFFFFFFFFu;
#pragma unroll
  for (int e = 0; e < 20; ++e)
    topk_insert<8>(mh, entS[row_s][half * 20 + e]);
#pragma unroll
  for (int s = 0; s < 8; ++s) hS[row_s][half * 8 + s] = mh[s];
  __syncthreads();
  if (!half) {
#pragma unroll
    for (int e = 0; e < 8; ++e) topk_insert<8>(mh, hS[row_s][8 + e]);
    const int irow = ib * 128 + row_s;
#pragma unroll
    for (int s = 0; s < 8; ++s)
      partials[(size_t)irow * PENT + jc * 8 + s] = mh[s];
  }
}

// ---- Kernel C: wave-per-row rescore (r17 structure) + sum-all/subtract ----
__global__ __launch_bounds__(256) void knn_rescore(
    const float* __restrict__ x, const uint32* __restrict__ partials,
    float* __restrict__ out) {
  const int l = threadIdx.x & 63;
  const int row = blockIdx.x * 4 + (threadIdx.x >> 6);

  // Load 256 partial keys (4/lane), drop self, full sort.
  uint4 pv = *(const uint4*)&partials[(size_t)row * PENT + l * 4];
  uint32 v0 = pv.x, v1 = pv.y, v2 = pv.z, v3 = pv.w;
  if ((v0 & 0x1FFFu) == (uint32)row) v0 = 0xFFFFFFFFu;
  if ((v1 & 0x1FFFu) == (uint32)row) v1 = 0xFFFFFFFFu;
  if ((v2 & 0x1FFFu) == (uint32)row) v2 = 0xFFFFFFFFu;
  if ((v3 & 0x1FFFu) == (uint32)row) v3 = 0xFFFFFFFFu;
  sort256(v0, v1, v2, v3, l);
  const int myj = (int)(v0 & 0x1FFFu);  // lane c < CC holds candidate c

  const float4* x4 = (const float4*)x;
  float4 xi0 = x4[(size_t)row * 128 + l];
  float4 xi1 = x4[(size_t)row * 128 + 64 + l];

  // fp32 d2 for all CC candidates + running sum of all candidate rows.
  float4 sa0 = make_float4(0.f, 0.f, 0.f, 0.f);
  float4 sa1 = make_float4(0.f, 0.f, 0.f, 0.f);
  float d2v = 0.f;
#pragma unroll
  for (int c = 0; c < CC; ++c) {
    const int j = __shfl(myj, c);
    float4 b0 = x4[(size_t)j * 128 + l];
    float4 b1 = x4[(size_t)j * 128 + 64 + l];
    float s = 0.f;
    float d0 = xi0.x - b0.x, d1 = xi0.y - b0.y;
    float d2 = xi0.z - b0.z, d3 = xi0.w - b0.w;
    s = fmaf(d0, d0, s); s = fmaf(d1, d1, s);
    s = fmaf(d2, d2, s); s = fmaf(d3, d3, s);
    d0 = xi1.x - b1.x; d1 = xi1.y - b1.y;
    d2 = xi1.z - b1.z; d3 = xi1.w - b1.w;
    s = fmaf(d0, d0, s); s = fmaf(d1, d1, s);
    s = fmaf(d2, d2, s); s = fmaf(d3, d3, s);
    sa0.x += b0.x; sa0.y += b0.y; sa0.z += b0.z; sa0.w += b0.w;
    sa1.x += b1.x; sa1.y += b1.y; sa1.z += b1.z; sa1.w += b1.w;
#pragma unroll
    for (int off = 32; off > 0; off >>= 1) s += __shfl_xor(s, off);
    if (l == c) d2v = s;
  }

  // fp32 rank (index tie-break).
  int rank = 0;
#pragma unroll
  for (int o = 0; o < CC; ++o) {
    float vo = __shfl(d2v, o);
    int io = __shfl(myj, o);
    if (vo < d2v || (vo == d2v && io < myj)) rank++;
  }

  // Gap test: exact set iff d2[rank16] - d2[rank15] > GAPTHR (err <= 2.5e-4).
  unsigned long long b15 = __ballot(l < CC && rank == KK - 1);
  unsigned long long b16 = __ballot(l < CC && rank == KK);
  float k15 = __shfl(d2v, (int)(__ffsll(b15) - 1));
  float k16 = __shfl(d2v, (int)(__ffsll(b16) - 1));
  if (k16 - k15 < GAPTHR) {  // rare: exact fp64 re-rank
    double dd = 0.0;
#pragma unroll
    for (int c = 0; c < CC; ++c) {
      const int j = __shfl(myj, c);
      float4 b0 = x4[(size_t)j * 128 + l];
      float4 b1 = x4[(size_t)j * 128 + 64 + l];
      double s = 0.0;
      double d0 = (double)xi0.x - (double)b0.x;
      double d1 = (double)xi0.y - (double)b0.y;
      double d2 = (double)xi0.z - (double)b0.z;
      double d3 = (double)xi0.w - (double)b0.w;
      s = fma(d0, d0, s); s = fma(d1, d1, s);
      s = fma(d2, d2, s); s = fma(d3, d3, s);
      d0 = (double)xi1.x - (double)b1.x;
      d1 = (double)xi1.y - (double)b1.y;
      d2 = (double)xi1.z - (double)b1.z;
      d3 = (double)xi1.w - (double)b1.w;
      s = fma(d0, d0, s); s = fma(d1, d1, s);
      s = fma(d2, d2, s); s = fma(d3, d3, s);
#pragma unroll
      for (int off = 32; off > 0; off >>= 1) s += __shfl_xor(s, off);
      if (l == c) dd = s;
    }
    rank = 0;
#pragma unroll
    for (int o = 0; o < CC; ++o) {
      double vo = __shfl(dd, o);
      int io = __shfl(myj, o);
      if (vo < dd || (vo == dd && io < myj)) rank++;
    }
  }

  // Subtract the 8 unselected rows (L1/L2-hot; wave-uniform branch).
  const unsigned long long selmask = __ballot(l < CC && rank < KK);
#pragma unroll
  for (int c = 0; c < CC; ++c) {
    if (!((selmask >> c) & 1ull)) {
      const int j = __shfl(myj, c);
      float4 b0 = x4[(size_t)j * 128 + l];
      float4 b1 = x4[(size_t)j * 128 + 64 + l];
      sa0.x -= b0.x; sa0.y -= b0.y; sa0.z -= b0.z; sa0.w -= b0.w;
      sa1.x -= b1.x; sa1.y -= b1.y; sa1.z -= b1.z; sa1.w -= b1.w;
    }
  }
  float4* o4 = (float4*)out;
  o4[(size_t)row * 128 + l] = make_float4(sa0.x * 0.0625f, sa0.y * 0.0625f,
                                          sa0.z * 0.0625f, sa0.w * 0.0625f);
  o4[(size_t)row * 128 + 64 + l] = make_float4(
      sa1.x * 0.0625f, sa1.y * 0.0625f, sa1.z * 0.0625f, sa1.w * 0.0625f);
}

extern "C" void kernel_launch(void* const* d_in, const int* in_sizes, int n_in,
                              void* d_out, int out_size, void* d_ws,
                              size_t ws_size, hipStream_t stream) {
  const float* x = (const float*)d_in[0];
  float* out = (float*)d_out;
  char* ws = (char*)d_ws;
  // ws layout: xq (4MB) | sqs (64KB) | partials (8MB)  => 12.1 MB
  uint4* xq = (uint4*)ws;
  float2* sqs = (float2*)(ws + (size_t)Nn * Dd);
  uint32* partials = (uint32*)(ws + (size_t)Nn * Dd + (size_t)Nn * 8);

  knn_prep<<<Nn / 8, 256, 0, stream>>>(x, xq, sqs);
  knn_cand<<<64 * JSPLIT, 256, 0, stream>>>(xq, sqs, partials);
  knn_rescore<<<Nn / 4, 256, 0, stream>>>(x, partials, out);
}

// Round 21
// 103.386 us; speedup vs baseline: 1.4916x; 1.4916x over previous
//
#include <hip/hip_runtime.h>
#include <hip/hip_bf16.h>

#define Nn 8192
#define Dd 512
#define KK 16
#define CC 24      // rescored candidates per row (CC=20 FAILED correctness r20)
#define CSUB 5     // per-lane reservoir size in knn_cand
#define JSPLIT 32  // 32 J-chunks of 256 rows; 4 per XCD
#define PENT 256   // partial entries per row (32 jc x 8)
#define GAPTHR 0.01f  // fp32-vs-fp64 selection gap threshold (err <= 2.5e-4)

typedef int i32x4 __attribute__((ext_vector_type(4)));
typedef unsigned int uint32;

__device__ __forceinline__ uint32 med3u(uint32 a, uint32 b, uint32 c) {
  uint32 d;
  asm("v_med3_u32 %0, %1, %2, %3" : "=v"(d) : "v"(a), "v"(b), "v"(c));
  return d;
}

// Branchless top-k (smallest keys) in a descending-sorted register array.
template <int CCn>
__device__ __forceinline__ void topk_insert(uint32* h, uint32 v) {
#pragma unroll
  for (int s = 0; s < CCn - 1; ++s) h[s] = med3u(h[s], h[s + 1], v);
  h[CCn - 1] = (h[CCn - 1] < v) ? h[CCn - 1] : v;
}

// ---- Barrier-free bitonic: compare-exchange with shfl partner (j <= 32) ----
__device__ __forceinline__ uint32 cswap(uint32 v, int j, bool asc, int lane) {
  uint32 pv = (uint32)__shfl_xor((int)v, j, 64);
  uint32 mn = v < pv ? v : pv;
  uint32 mx = v < pv ? pv : v;
  const bool lower = ((lane & j) == 0);
  return (asc == lower) ? mn : mx;
}

__device__ __forceinline__ void cmpx(uint32& a, uint32& b, bool asc) {
  uint32 mn = a < b ? a : b;
  uint32 mx = a < b ? b : a;
  a = asc ? mn : mx;
  b = asc ? mx : mn;
}

// Full ascending bitonic sort of 256 uint keys, 4 per lane.
__device__ __forceinline__ void sort256(uint32& v0, uint32& v1, uint32& v2,
                                        uint32& v3, int lane) {
#pragma unroll
  for (int k = 2; k <= 32; k <<= 1) {
#pragma unroll
    for (int j = k >> 1; j > 0; j >>= 1) {
      const bool asc = ((lane & k) == 0);
      v0 = cswap(v0, j, asc, lane);
      v1 = cswap(v1, j, asc, lane);
      v2 = cswap(v2, j, asc, lane);
      v3 = cswap(v3, j, asc, lane);
    }
  }
#pragma unroll
  for (int j = 32; j > 0; j >>= 1) {
    v0 = cswap(v0, j, true, lane);
    v1 = cswap(v1, j, false, lane);
    v2 = cswap(v2, j, true, lane);
    v3 = cswap(v3, j, false, lane);
  }
  cmpx(v0, v1, true);
  cmpx(v2, v3, false);
#pragma unroll
  for (int j = 32; j > 0; j >>= 1) {
    v0 = cswap(v0, j, true, lane);
    v1 = cswap(v1, j, true, lane);
    v2 = cswap(v2, j, false, lane);
    v3 = cswap(v3, j, false, lane);
  }
  cmpx(v0, v2, true);
  cmpx(v1, v3, true);
  cmpx(v0, v1, true);
  cmpx(v2, v3, true);
#pragma unroll
  for (int j = 32; j > 0; j >>= 1) {
    v0 = cswap(v0, j, true, lane);
    v1 = cswap(v1, j, true, lane);
    v2 = cswap(v2, j, true, lane);
    v3 = cswap(v3, j, true, lane);
  }
}

// -------- Kernel A: fp32 -> int8 (per-row symmetric), cc'-major frag order --------
// One wave = 2 rows; lane handles 16 cols = exactly one xq frag. No LDS.
__global__ void knn_prep(const float* __restrict__ x, uint4* __restrict__ xq,
                         float2* __restrict__ sqs) {
  const int t = threadIdx.x;
  const int w = t >> 6, l = t & 63;
  const int row = blockIdx.x * 8 + w * 2 + (l >> 5);
  const int cc = l & 31;
  const float4* xr = (const float4*)(x + (size_t)row * Dd + cc * 16);
  float4 a = xr[0], b = xr[1], c = xr[2], d = xr[3];
  float s = 0.f, amax = 0.f;
#pragma unroll
  for (int q = 0; q < 4; ++q) {
    float4 v = (q == 0) ? a : (q == 1) ? b : (q == 2) ? c : d;
    s = fmaf(v.x, v.x, s); s = fmaf(v.y, v.y, s);
    s = fmaf(v.z, v.z, s); s = fmaf(v.w, v.w, s);
    amax = fmaxf(amax, fmaxf(fmaxf(fabsf(v.x), fabsf(v.y)),
                             fmaxf(fabsf(v.z), fabsf(v.w))));
  }
#pragma unroll
  for (int j = 1; j <= 16; j <<= 1) {  // reduce within 32-lane row group
    s += __shfl_xor(s, j);
    amax = fmaxf(amax, __shfl_xor(amax, j));
  }
  const float inv = (amax > 0.f) ? (127.f / amax) : 0.f;
  if (cc == 0) sqs[row] = make_float2(s, amax * (1.f / 127.f));
  uint32 wds[4];
#pragma unroll
  for (int q = 0; q < 4; ++q) {
    float4 v = (q == 0) ? a : (q == 1) ? b : (q == 2) ? c : d;
    const float vv[4] = {v.x, v.y, v.z, v.w};
    uint32 bb = 0;
#pragma unroll
    for (int e = 0; e < 4; ++e) {
      int qi = __float2int_rn(vv[e] * inv);
      bb |= ((uint32)(qi & 0xFF)) << (8 * e);
    }
    wds[q] = bb;
  }
  const int rb = row >> 4, r16 = row & 15;
  xq[((size_t)cc * 512 + rb) * 16 + r16] =
      make_uint4(wds[0], wds[1], wds[2], wds[3]);
}

// ------- Kernel B: barrier-free i8 MFMA (K=64/instr), 64x128 wave tile -------
__global__ __launch_bounds__(256, 2) void knn_cand(
    const uint4* __restrict__ xqv, const float2* __restrict__ sqs,
    uint32* __restrict__ partials) {
  __shared__ uint32 entS[128][41];  // 21 KB
  __shared__ uint32 hS[128][16];    // 8 KB

  const int bid = blockIdx.x;
  const int xcd = bid & 7;
  const int jc = xcd * 4 + ((bid >> 3) & 3);  // [0,32)
  const int ib = bid >> 5;                    // [0,64)
  const int t = threadIdx.x;
  const int w = t >> 6;
  const int l = t & 63;
  const int wrow = w >> 1, wcol = w & 1;
  const int l16 = l & 15, lq = l >> 4;

  const i32x4* xf = (const i32x4*)xqv;
  const int abase = ib * 8 + wrow * 4;
  const int bbase = jc * 16 + wcol * 8;  // 8 rb-blocks = 128 j-rows
  const int jbase = jc * 256;

  const i32x4* pA0 = xf + ((size_t)lq * 512 + abase) * 16 + l16;
  const i32x4* pB0 = xf + ((size_t)lq * 512 + bbase) * 16 + l16;

#define LDSET(fa, fb, s)                                              \
  do {                                                                \
    const i32x4* pa = pA0 + (size_t)(s)*32768;                        \
    const i32x4* pb = pB0 + (size_t)(s)*32768;                        \
    _Pragma("unroll") for (int q = 0; q < 4; ++q) fa[q] = pa[q * 16]; \
    _Pragma("unroll") for (int q = 0; q < 8; ++q) fb[q] = pb[q * 16]; \
  } while (0)

  uint32 heap[4][CSUB];
#pragma unroll
  for (int fi = 0; fi < 4; ++fi)
#pragma unroll
    for (int s = 0; s < CSUB; ++s) heap[fi][s] = 0xFFFFFFFFu;

  i32x4 acc[4][8];
#pragma unroll
  for (int a = 0; a < 4; ++a)
#pragma unroll
    for (int b = 0; b < 8; ++b) acc[a][b] = (i32x4){0, 0, 0, 0};

  i32x4 fa0[4], fb0[8], fa1[4], fb1[8];
  LDSET(fa0, fb0, 0);

#pragma unroll 1
  for (int s = 0; s < 8; s += 2) {
    LDSET(fa1, fb1, s + 1);
    __builtin_amdgcn_s_setprio(1);
#pragma unroll
    for (int fi = 0; fi < 4; ++fi)
#pragma unroll
      for (int fj = 0; fj < 8; ++fj)
        acc[fi][fj] = __builtin_amdgcn_mfma_i32_16x16x64_i8(
            fb0[fj], fa0[fi], acc[fi][fj], 0, 0, 0);  // swapped: C^T
    __builtin_amdgcn_s_setprio(0);
    if (s + 2 < 8) LDSET(fa0, fb0, s + 2);
    __builtin_amdgcn_s_setprio(1);
#pragma unroll
    for (int fi = 0; fi < 4; ++fi)
#pragma unroll
      for (int fj = 0; fj < 8; ++fj)
        acc[fi][fj] = __builtin_amdgcn_mfma_i32_16x16x64_i8(
            fb1[fj], fa1[fi], acc[fi][fj], 0, 0, 0);
    __builtin_amdgcn_s_setprio(0);
  }
#undef LDSET

  // In-register selection: key = sq_j - 2 s_i s_j dot (>=0 clamp).
  float mi[4];
#pragma unroll
  for (int fi = 0; fi < 4; ++fi)
    mi[fi] = -2.f * sqs[ib * 128 + wrow * 64 + fi * 16 + l16].y;
  const uint32 jg_base = (uint32)(jbase + wcol * 128 + lq * 4);
#pragma unroll
  for (int fj = 0; fj < 8; ++fj) {
    const float2* sp = &sqs[jbase + wcol * 128 + fj * 16 + lq * 4];
    float4 p0 = *(const float4*)sp;        // (sq0,s0,sq1,s1)
    float4 p1 = *(const float4*)(sp + 2);  // (sq2,s2,sq3,s3)
    const float sv[4] = {p0.x, p0.z, p1.x, p1.z};
    const float ss[4] = {p0.y, p0.w, p1.y, p1.w};
#pragma unroll
    for (int r = 0; r < 4; ++r) {
      const uint32 jg = jg_base + (uint32)(fj * 16 + r);
#pragma unroll
      for (int fi = 0; fi < 4; ++fi) {
        float key =
            fmaxf(fmaf(mi[fi] * ss[r], (float)acc[fi][fj][r], sv[r]), 0.f);
        uint32 packed = (__builtin_bit_cast(uint32, key) & 0xFFFFE000u) | jg;
        topk_insert<CSUB>(heap[fi], packed);  // self removed in rescore
      }
    }
  }

  // Merge: 8 lane-reservoirs (40 entries) per row -> top-8 per (row, jc).
#pragma unroll
  for (int fi = 0; fi < 4; ++fi)
#pragma unroll
    for (int s = 0; s < CSUB; ++s)
      entS[wrow * 64 + fi * 16 + l16][(wcol * 4 + lq) * CSUB + s] =
          heap[fi][s];
  __syncthreads();

  const int row_s = t >> 1, half = t & 1;
  uint32 mh[8];
#pragma unroll
  for (int s = 0; s < 8; ++s) mh[s] = 0xFFFFFFFFu;
#pragma unroll
  for (int e = 0; e < 20; ++e)
    topk_insert<8>(mh, entS[row_s][half * 20 + e]);
#pragma unroll
  for (int s = 0; s < 8; ++s) hS[row_s][half * 8 + s] = mh[s];
  __syncthreads();
  if (!half) {
#pragma unroll
    for (int e = 0; e < 8; ++e) topk_insert<8>(mh, hS[row_s][8 + e]);
    const int irow = ib * 128 + row_s;
#pragma unroll
    for (int s = 0; s < 8; ++s)
      partials[(size_t)irow * PENT + jc * 8 + s] = mh[s];
  }
}

// ---- Kernel C: wave-per-row rescore (r17 structure, low-VGPR, CC=24) ----
// sort256 in registers -> fp32 d2 + gap test (fp64 fallback) -> average.
__global__ __launch_bounds__(256) void knn_rescore(
    const float* __restrict__ x, const uint32* __restrict__ partials,
    float* __restrict__ out) {
  const int l = threadIdx.x & 63;
  const int row = blockIdx.x * 4 + (threadIdx.x >> 6);

  // Load 256 partial keys (4/lane), drop self, full sort.
  uint4 pv = *(const uint4*)&partials[(size_t)row * PENT + l * 4];
  uint32 v0 = pv.x, v1 = pv.y, v2 = pv.z, v3 = pv.w;
  if ((v0 & 0x1FFFu) == (uint32)row) v0 = 0xFFFFFFFFu;
  if ((v1 & 0x1FFFu) == (uint32)row) v1 = 0xFFFFFFFFu;
  if ((v2 & 0x1FFFu) == (uint32)row) v2 = 0xFFFFFFFFu;
  if ((v3 & 0x1FFFu) == (uint32)row) v3 = 0xFFFFFFFFu;
  sort256(v0, v1, v2, v3, l);
  const int myj = (int)(v0 & 0x1FFFu);  // lane c < CC holds candidate c

  const float4* x4 = (const float4*)x;
  float4 xi0 = x4[(size_t)row * 128 + l];
  float4 xi1 = x4[(size_t)row * 128 + 64 + l];

  // fp32 d2 for all CC candidates; candidate c's d2 lands on lane c.
  float d2v = 0.f;
#pragma unroll
  for (int c = 0; c < CC; ++c) {
    const int j = __shfl(myj, c);
    float4 b0 = x4[(size_t)j * 128 + l];
    float4 b1 = x4[(size_t)j * 128 + 64 + l];
    float s = 0.f;
    float d0 = xi0.x - b0.x, d1 = xi0.y - b0.y;
    float d2 = xi0.z - b0.z, d3 = xi0.w - b0.w;
    s = fmaf(d0, d0, s); s = fmaf(d1, d1, s);
    s = fmaf(d2, d2, s); s = fmaf(d3, d3, s);
    d0 = xi1.x - b1.x; d1 = xi1.y - b1.y;
    d2 = xi1.z - b1.z; d3 = xi1.w - b1.w;
    s = fmaf(d0, d0, s); s = fmaf(d1, d1, s);
    s = fmaf(d2, d2, s); s = fmaf(d3, d3, s);
#pragma unroll
    for (int off = 32; off > 0; off >>= 1) s += __shfl_xor(s, off);
    if (l == c) d2v = s;
  }

  // fp32 rank (index tie-break).
  int rank = 0;
#pragma unroll
  for (int o = 0; o < CC; ++o) {
    float vo = __shfl(d2v, o);
    int io = __shfl(myj, o);
    if (vo < d2v || (vo == d2v && io < myj)) rank++;
  }

  // Gap test: exact set iff d2[rank16] - d2[rank15] > GAPTHR (err <= 2.5e-4).
  unsigned long long b15 = __ballot(l < CC && rank == KK - 1);
  unsigned long long b16 = __ballot(l < CC && rank == KK);
  float k15 = __shfl(d2v, (int)(__ffsll(b15) - 1));
  float k16 = __shfl(d2v, (int)(__ffsll(b16) - 1));
  if (k16 - k15 < GAPTHR) {  // rare: exact fp64 re-rank
    double dd = 0.0;
#pragma unroll
    for (int c = 0; c < CC; ++c) {
      const int j = __shfl(myj, c);
      float4 b0 = x4[(size_t)j * 128 + l];
      float4 b1 = x4[(size_t)j * 128 + 64 + l];
      double s = 0.0;
      double d0 = (double)xi0.x - (double)b0.x;
      double d1 = (double)xi0.y - (double)b0.y;
      double d2 = (double)xi0.z - (double)b0.z;
      double d3 = (double)xi0.w - (double)b0.w;
      s = fma(d0, d0, s); s = fma(d1, d1, s);
      s = fma(d2, d2, s); s = fma(d3, d3, s);
      d0 = (double)xi1.x - (double)b1.x;
      d1 = (double)xi1.y - (double)b1.y;
      d2 = (double)xi1.z - (double)b1.z;
      d3 = (double)xi1.w - (double)b1.w;
      s = fma(d0, d0, s); s = fma(d1, d1, s);
      s = fma(d2, d2, s); s = fma(d3, d3, s);
#pragma unroll
      for (int off = 32; off > 0; off >>= 1) s += __shfl_xor(s, off);
      if (l == c) dd = s;
    }
    rank = 0;
#pragma unroll
    for (int o = 0; o < CC; ++o) {
      double vo = __shfl(dd, o);
      int io = __shfl(myj, o);
      if (vo < dd || (vo == dd && io < myj)) rank++;
    }
  }

  // Average the 16 selected rows (wave-uniform branch; rows L1/L2-hot).
  const unsigned long long selmask = __ballot(l < CC && rank < KK);
  float4 a0 = make_float4(0.f, 0.f, 0.f, 0.f);
  float4 a1 = make_float4(0.f, 0.f, 0.f, 0.f);
#pragma unroll
  for (int c = 0; c < CC; ++c) {
    if ((selmask >> c) & 1ull) {
      const int j = __shfl(myj, c);
      float4 b0 = x4[(size_t)j * 128 + l];
      float4 b1 = x4[(size_t)j * 128 + 64 + l];
      a0.x += b0.x; a0.y += b0.y; a0.z += b0.z; a0.w += b0.w;
      a1.x += b1.x; a1.y += b1.y; a1.z += b1.z; a1.w += b1.w;
    }
  }
  float4* o4 = (float4*)out;
  o4[(size_t)row * 128 + l] =
      make_float4(a0.x * 0.0625f, a0.y * 0.0625f, a0.z * 0.0625f, a0.w * 0.0625f);
  o4[(size_t)row * 128 + 64 + l] =
      make_float4(a1.x * 0.0625f, a1.y * 0.0625f, a1.z * 0.0625f, a1.w * 0.0625f);
}

extern "C" void kernel_launch(void* const* d_in, const int* in_sizes, int n_in,
                              void* d_out, int out_size, void* d_ws,
                              size_t ws_size, hipStream_t stream) {
  const float* x = (const float*)d_in[0];
  float* out = (float*)d_out;
  char* ws = (char*)d_ws;
  // ws layout: xq (4MB) | sqs (64KB) | partials (8MB)  => 12.1 MB
  uint4* xq = (uint4*)ws;
  float2* sqs = (float2*)(ws + (size_t)Nn * Dd);
  uint32* partials = (uint32*)(ws + (size_t)Nn * Dd + (size_t)Nn * 8);

  knn_prep<<<Nn / 8, 256, 0, stream>>>(x, xq, sqs);
  knn_cand<<<64 * JSPLIT, 256, 0, stream>>>(xq, sqs, partials);
  knn_rescore<<<Nn / 4, 256, 0, stream>>>(x, partials, out);
}